// Round 13
// baseline (1890.023 us; speedup 1.0000x reference)
//
#include <hip/hip_runtime.h>
#include <hip/hip_bf16.h>

// ---------------------------------------------------------------------------
// MultiFieldAxialAttention on MI355X (gfx950)
// B=32, T=12, LA=12, LO=12, D0=1024, D1=512, H=8+8, E=64
//
// Folds: qkv_{ip+1} = concat_ip @ (W3[ip]@W1[ip+1]) + b@W1[ip+1]; all 3
// cross-KV projections in one N=3072 GEMM; both weight-fold GEMMs z-batched.
// Layout pipeline: layer-ip qkv GEMM gathers A rows via digit permutation
// (per-lane global_load_lds source) and writes qkv with the attention axis
// innermost; attention reads/writes fully contiguous fibers.
// GEMM (this round): 256x256x64, SINGLE 64KB LDS buffer -> 2 blocks/CU.
// m97-style loop {stage; vmcnt(0)+barrier; reads+MFMA; lgkmcnt(0)+barrier};
// cross-block TLP covers the drain (m114/m97 mechanism). 16x16x32 MFMA,
// conflict-free XOR swizzle (pre-swizzled global src, rule 21).
// Attention: bf16x8-vectorized LDS reads (dots + AV), uint4 stores.
// ---------------------------------------------------------------------------

typedef __bf16 bf16x8 __attribute__((ext_vector_type(8)));
typedef float floatx4 __attribute__((ext_vector_type(4)));

#define N0 55296   // 32*12*12*12 tokens of field0
#define N1 13824   // 32*12*6*6 tokens of field1

#define RAW_BARRIER() asm volatile("s_barrier" ::: "memory")
#define VMCNT(n) asm volatile("s_waitcnt vmcnt(" #n ")" ::: "memory")
#define LGKMCNT0() asm volatile("s_waitcnt lgkmcnt(0)" ::: "memory")

__device__ __forceinline__ void gload16(const void* g, void* l) {
    __builtin_amdgcn_global_load_lds(
        (const __attribute__((address_space(1))) unsigned int*)g,
        (__attribute__((address_space(3))) unsigned int*)l, 16, 0, 0);
}

// Row map: C physical row i -> A physical row.  Digits of i in its layout:
// SIG 1: C=L0 (la,lo,t)   -> A natural (t,la,lo)
// SIG 2: C=L1 (t,lo,la)   -> A L0 (la,lo,t)
// SIG 3: C=natural(t,la,lo)-> A L1 (t,lo,la)
template <int SIG>
__device__ __forceinline__ int mapRow(int i) {
    if (SIG == 0) return i;
    const int b = i / 1728, r = i % 1728;
    const int d1 = r / 144, r2 = r % 144, d2 = r2 / 12, d3 = r2 % 12;
    if (SIG == 1) return b * 1728 + d3 * 144 + d1 * 12 + d2;
    if (SIG == 2) return b * 1728 + d3 * 144 + d2 * 12 + d1;
    return b * 1728 + d1 * 144 + d3 * 12 + d2;
}

// ---------------------------------------------------------------------------
// LayerNorm: fp32 in -> bf16 out, 1 block per row; vectorized loads/stores
// ---------------------------------------------------------------------------
template <int D>
__device__ __forceinline__ void ln_body(const float* __restrict__ xr,
                                        __hip_bfloat16* __restrict__ yr)
{
    constexpr int V = D / 256;          // 4 (D=1024) or 2 (D=512)
    const int tid = threadIdx.x;
    float vals[V];
    if constexpr (V == 4) {
        const float4 t4 = *(const float4*)(xr + tid * 4);
        vals[0] = t4.x; vals[1] = t4.y; vals[2] = t4.z; vals[3] = t4.w;
    } else {
        const float2 t2 = *(const float2*)(xr + tid * 2);
        vals[0] = t2.x; vals[1] = t2.y;
    }
    float s = 0.f, q = 0.f;
#pragma unroll
    for (int k = 0; k < V; ++k) { s += vals[k]; q += vals[k] * vals[k]; }
#pragma unroll
    for (int off = 32; off > 0; off >>= 1) {
        s += __shfl_xor(s, off);
        q += __shfl_xor(q, off);
    }
    __shared__ float rs[4], rq[4];
    const int w = tid >> 6;
    if ((tid & 63) == 0) { rs[w] = s; rq[w] = q; }
    __syncthreads();
    s = rs[0] + rs[1] + rs[2] + rs[3];
    q = rq[0] + rq[1] + rq[2] + rq[3];
    const float mean = s * (1.f / D);
    const float var  = q * (1.f / D) - mean * mean;
    const float rstd = rsqrtf(var + 1e-5f);
    __hip_bfloat16 o[V];
#pragma unroll
    for (int k = 0; k < V; ++k) o[k] = __float2bfloat16((vals[k] - mean) * rstd);
    if constexpr (V == 4) *(uint2*)(yr + tid * 4) = *(const uint2*)o;
    else                  *(uint*)(yr + tid * 2)  = *(const uint*)o;
}

__global__ __launch_bounds__(256)
void ln_all(const float* __restrict__ x0, const float* __restrict__ x1,
            __hip_bfloat16* __restrict__ f0, __hip_bfloat16* __restrict__ f1)
{
    const int row = blockIdx.x;
    if (row < N0) {
        ln_body<1024>(x0 + (size_t)row * 1024, f0 + (size_t)row * 1024);
    } else {
        const int r = row - N0;
        ln_body<512>(x1 + (size_t)r * 512, f1 + (size_t)r * 512);
    }
}

// ---------------------------------------------------------------------------
// Weight transposes (W3t only for ip=2 -- ip 0,1 are folded away) + w_out
// bf16 cast, in ONE launch. transpose: [K][N] fp32 -> [N][K] bf16.
// ---------------------------------------------------------------------------
__global__ __launch_bounds__(256)
void transpose_all(const float* __restrict__ wqs, const float* __restrict__ wkvs,
                   const float* __restrict__ wqc, const float* __restrict__ wkvc,
                   const float* __restrict__ wo,
                   __hip_bfloat16* __restrict__ W1t,
                   __hip_bfloat16* __restrict__ W2t,
                   __hip_bfloat16* __restrict__ W3t,
                   __hip_bfloat16* __restrict__ W3o)
{
    int idx = blockIdx.x;
    if (idx >= 8704) {   // flat cast segment: w_out[0..1] -> W3o
        const size_t i = ((size_t)(idx - 8704) * 256 + threadIdx.x) * 4;
        const float4 v = *(const float4*)(wo + i);
        __hip_bfloat16 o[4] = { __float2bfloat16(v.x), __float2bfloat16(v.y),
                                __float2bfloat16(v.z), __float2bfloat16(v.w) };
        *(uint2*)(W3o + i) = *(const uint2*)o;
        return;
    }
    const float* src;
    __hip_bfloat16* dst;
    int K, N;
    if (idx < 1536) {
        const int ip = idx / 512; idx %= 512; K = 1024; N = 512;
        src = wqs + (size_t)ip * 524288;  dst = W1t + (size_t)ip * 2097152;
    } else if (idx < 4608) {
        idx -= 1536;
        const int ip = idx / 1024; idx %= 1024; K = 1024; N = 1024;
        src = wkvs + (size_t)ip * 1048576; dst = W1t + (size_t)ip * 2097152 + 524288;
    } else if (idx < 6144) {
        idx -= 4608;
        const int ip = idx / 512; idx %= 512; K = 1024; N = 512;
        src = wqc + (size_t)ip * 524288;  dst = W1t + (size_t)ip * 2097152 + 1572864;
    } else if (idx < 7680) {
        idx -= 6144;
        const int ip = idx / 512; idx %= 512; K = 512; N = 1024;
        src = wkvc + (size_t)ip * 524288; dst = W2t + (size_t)ip * 524288;
    } else {
        idx -= 7680;   // [0,1024): w_out ip=2 only
        K = 1024; N = 1024;
        src = wo + (size_t)2 * 1048576;  dst = W3t + (size_t)2 * 1048576;
    }
    const int tiles_x = N >> 5;
    const int n0 = (idx % tiles_x) * 32, k0 = (idx / tiles_x) * 32;

    __shared__ float tile[32][33];
    const int tx = threadIdx.x & 31, ty = threadIdx.x >> 5; // 32 x 8
#pragma unroll
    for (int d = 0; d < 4; ++d)
        tile[ty + d * 8][tx] = src[(size_t)(k0 + ty + d * 8) * N + n0 + tx];
    __syncthreads();
#pragma unroll
    for (int d = 0; d < 4; ++d)
        dst[(size_t)(n0 + ty + d * 8) * K + k0 + tx] = __float2bfloat16(tile[tx][ty + d * 8]);
}

// ---------------------------------------------------------------------------
// Folded bias: bf[j][n] = sum_d b_out[j][d] * W1[j+1][d][n]  (j = 0,1)
// ---------------------------------------------------------------------------
__global__ __launch_bounds__(256)
void bfold_kernel(const float* __restrict__ b_out,
                  const __hip_bfloat16* __restrict__ W1t,
                  float* __restrict__ bf)
{
    const int idx = blockIdx.x * 256 + threadIdx.x;   // [0, 4096)
    const int j = idx >> 11, n = idx & 2047;
    const float* b = b_out + j * 1024;
    const __hip_bfloat16* w = W1t + ((size_t)(j + 1) * 2048 + n) * 1024;
    float s = 0.f;
#pragma unroll 4
    for (int d = 0; d < 1024; ++d) s += b[d] * __bfloat162float(w[d]);
    bf[idx] = s;
}

// ---------------------------------------------------------------------------
// 256x256 bf16 MFMA GEMM: C[M,N] = A[sigma(M),K] @ Bt[N,K]^T
// 512 thr = 8 waves (2Mx4N), per-wave 128x64 out, 16x16x32 MFMA, BK=64,
// SINGLE 64KB LDS buffer -> 2 blocks/CU. Loop per K-tile:
//   stage A,B (8 gloads) ; vmcnt(0)+barrier ; 24 ds_read_b128 + 64 MFMA ;
//   lgkmcnt(0)+barrier.
// Within-block drain is exposed; the co-resident block's MFMA covers it
// (m114 TLP). XOR swizzle on 16B col-groups (pre-swizzled global source,
// rule 21) = 0 bank conflicts.
// zsA/zsB/zsC: blockIdx.z batch strides in elements.
// EPI: 0 = bf16 ; 1 = bf16+bias ; 2 = fp32+bias+resid
// ---------------------------------------------------------------------------
template <int EPI, int SIG>
__global__ __launch_bounds__(512)
void gemm8p(const __hip_bfloat16* __restrict__ A,
            const __hip_bfloat16* __restrict__ Bt,
            void* __restrict__ Cv,
            const float* __restrict__ bias,
            const float* __restrict__ resid,
            int M, int N, int K, int lda,
            size_t zsA, size_t zsB, size_t zsC)
{
    __shared__ __align__(16) char lds[65536];

    A  += (size_t)blockIdx.z * zsA;
    Bt += (size_t)blockIdx.z * zsB;
    Cv = (void*)((__hip_bfloat16*)Cv + (size_t)blockIdx.z * zsC);

    // bijective XCD swizzle (all grids are multiples of 8 workgroups per z)
    const int gx  = gridDim.x;
    const int nwg = gx * gridDim.y;
    const int bid = blockIdx.y * gx + blockIdx.x;
    const int swz = (bid & 7) * (nwg >> 3) + (bid >> 3);
    const int m0 = (swz / gx) * 256;
    const int n0 = (swz % gx) * 256;

    const int t    = threadIdx.x;
    const int w    = t >> 6;
    const int lane = t & 63;
    const int wr   = w >> 2;     // 0..1  (M half)
    const int wc   = w & 3;      // 0..3  (N quarter)
    const int fr   = lane & 15;
    const int ksl  = lane >> 4;

    floatx4 acc[8][4] = {};

    // ---- staging source bases (pre-swizzled col: key = local row & 7)
    const int tr   = t >> 3;                      // 0..63
    const int scol = ((t & 7) ^ (tr & 7)) << 3;
    const __hip_bfloat16* aP[4];
#pragma unroll
    for (int r = 0; r < 4; ++r)
        aP[r] = A + (size_t)mapRow<SIG>(m0 + tr + r * 64) * lda + scol;
    const __hip_bfloat16* bG = Bt + (size_t)(n0 + ((tr >> 5) * 64) + (tr & 31)) * K + scol;
    const int ldst = t * 16;                      // linear LDS dest

    // ---- ds_read per-thread base offsets (kk=1 via ^64)
    const int cg0 = ksl ^ (fr & 7);
    const int aO0 = (wr * 64 + fr) * 128 + cg0 * 16;
    const int bO0 = (wc * 32 + fr) * 128 + cg0 * 16;

    // LDS map (64 KiB): A-h0 @0, A-h1 @16384, B-h0 @32768, B-h1 @49152
    auto stageA = [&](int h, int ka) {
        gload16(aP[h]     + ka, lds + h * 16384 + ldst);
        gload16(aP[h + 2] + ka, lds + h * 16384 + 8192 + ldst);
    };
    auto stageB = [&](int h, int kb) {
        gload16(bG + kb + (size_t)(h * 32)       * K, lds + 32768 + h * 16384 + ldst);
        gload16(bG + kb + (size_t)(h * 32 + 128) * K, lds + 32768 + h * 16384 + 8192 + ldst);
    };

    auto ldA = [&](int h, bf16x8 (&a)[2][4]) {
#pragma unroll
        for (int mm = 0; mm < 4; ++mm) {
            a[0][mm] = *(const bf16x8*)(lds + h * 16384 + mm * 2048 + aO0);
            a[1][mm] = *(const bf16x8*)(lds + h * 16384 + mm * 2048 + (aO0 ^ 64));
        }
    };
    auto ldB = [&](int h, bf16x8 (&b)[2][2]) {
#pragma unroll
        for (int nn = 0; nn < 2; ++nn) {
            b[0][nn] = *(const bf16x8*)(lds + 32768 + h * 16384 + nn * 2048 + bO0);
            b[1][nn] = *(const bf16x8*)(lds + 32768 + h * 16384 + nn * 2048 + (bO0 ^ 64));
        }
    };
    auto quad = [&](bf16x8 (&a)[2][4], bf16x8 (&b)[2][2], int mlo, int nlo) {
        __builtin_amdgcn_s_setprio(1);
#pragma unroll
        for (int kk = 0; kk < 2; ++kk)
#pragma unroll
            for (int mm = 0; mm < 4; ++mm)
#pragma unroll
                for (int nn = 0; nn < 2; ++nn)
                    acc[mlo + mm][nlo + nn] = __builtin_amdgcn_mfma_f32_16x16x32_bf16(
                        a[kk][mm], b[kk][nn], acc[mlo + mm][nlo + nn], 0, 0, 0);
        __builtin_amdgcn_s_setprio(0);
    };

    const int NT = K >> 6;
    bf16x8 a0[2][4], a1[2][4], b0[2][2], b1[2][2];

    for (int tt = 0; tt < NT; ++tt) {
        const int kc = tt << 6;
        // stage full tile (A0,B0,A1,B1)
        stageA(0, kc);
        stageB(0, kc);
        stageA(1, kc);
        stageB(1, kc);
        VMCNT(0); RAW_BARRIER();
        // read fragments + 64 MFMA (compiler interleaves; MFMAs may sink
        // past the end barrier and overlap next tile's staging)
        ldA(0, a0); ldB(0, b0);
        quad(a0, b0, 0, 0);
        ldA(1, a1);
        quad(a1, b0, 4, 0);
        ldB(1, b1);
        quad(a0, b1, 0, 2);
        quad(a1, b1, 4, 2);
        LGKMCNT0();   // all ds_reads retired before next overwrite
        RAW_BARRIER();
    }

    // ---- epilogue (C rows are physically linear)
#pragma unroll
    for (int m = 0; m < 8; ++m) {
#pragma unroll
        for (int n = 0; n < 4; ++n) {
            const int col = n0 + wc * 64 + n * 16 + fr;
#pragma unroll
            for (int r = 0; r < 4; ++r) {
                const int row = m0 + wr * 128 + m * 16 + ksl * 4 + r;
                const size_t idx = (size_t)row * N + col;
                const float v = acc[m][n][r];
                if (EPI == 0) {
                    ((__hip_bfloat16*)Cv)[idx] = __float2bfloat16(v);
                } else if (EPI == 1) {
                    ((__hip_bfloat16*)Cv)[idx] = __float2bfloat16(v + bias[col]);
                } else {
                    ((float*)Cv)[idx] = resid[idx] + v + bias[col];
                }
            }
        }
    }
}

// ---------------------------------------------------------------------------
// Fused axial attention (self + cross in one block), layout-contiguous,
// bf16x8-vectorized LDS reads.
// qkv rows [g*12, g*12+12) in layer layout L(ip): [q_self|k_self|v_self|q_cross]
// kvc: layer slice of kvc3 (row stride 3072): [k_cross(512) | v_cross(512)]
// out: concat [o_self|o_cross] rows [g*12, g*12+12), ld 1024 (layout L(ip))
// ---------------------------------------------------------------------------
__global__ __launch_bounds__(512)
void attn_fused(const __hip_bfloat16* __restrict__ qkv,
                const __hip_bfloat16* __restrict__ kvc,
                __hip_bfloat16* __restrict__ out, int ip)
{
    __shared__ __align__(16) __hip_bfloat16 R[12][2056];   // rows 4112B = 16B-aligned
    __shared__ __align__(16) __hip_bfloat16 KV[12][1032];  // rows 2064B = 16B-aligned
    __shared__ __hip_bfloat16 P[16][12][12];               // 8 self + 8 cross

    const int g   = blockIdx.x;           // 4608 fibers
    const int tid = threadIdx.x;

    // decode fiber -> cross-kv base (g digits are in layout L(ip) order)
    const int b  = g / 144;
    const int u1 = (g / 12) % 12;
    const int u2 = g % 12;
    int kvb, kvstride, tkc;
    if (ip == 0) {        // L0 fiber coords (la, lo); kv along t
        kvb = b * 432 + (u1 >> 1) * 6 + (u2 >> 1); kvstride = 36; tkc = 12;
    } else if (ip == 1) { // L1 fiber coords (t, lo); kv along la'
        kvb = b * 432 + u1 * 36 + (u2 >> 1); kvstride = 6; tkc = 6;
    } else {              // natural fiber coords (t, la); kv along lo'
        kvb = b * 432 + u1 * 36 + (u2 >> 1) * 6; kvstride = 1; tkc = 6;
    }

    // ---- stage 12 full rows (48KB contiguous)
    const uint4* src = (const uint4*)(qkv + (size_t)g * 12 * 2048);
    for (int idx = tid; idx < 12 * 256; idx += 512) {
        const int row = idx >> 8, cg = idx & 255;
        *(uint4*)(&R[row][cg * 8]) = src[row * 256 + cg];
    }
    // ---- stage cross K/V (2KB per kv row)
    for (int idx = tid; idx < tkc * 128; idx += 512) {
        const int row = idx >> 7, cg = idx & 127;
        const uint4* kvr = (const uint4*)(kvc + (size_t)(kvb + row * kvstride) * 3072);
        *(uint4*)(&KV[row][cg * 8]) = kvr[cg];
    }
    __syncthreads();

    // ---- dots (self: 1152, cross: 8*12*tkc), bf16x8 reads
    const int nd_self = 8 * 12 * 12;
    const int nd = nd_self + 8 * 12 * tkc;
    for (int idx = tid; idx < nd; idx += 512) {
        int h, i, j;
        const bf16x8 *q8, *k8;
        const bool self = idx < nd_self;
        if (self) {
            h = idx / 144; const int rem = idx % 144; i = rem / 12; j = rem % 12;
            q8 = (const bf16x8*)(&R[i][h * 64]);
            k8 = (const bf16x8*)(&R[j][512 + h * 64]);
        } else {
            const int x = idx - nd_self;
            h = x / (12 * tkc); const int rem = x % (12 * tkc); i = rem / tkc; j = rem % tkc;
            q8 = (const bf16x8*)(&R[i][1536 + h * 64]);
            k8 = (const bf16x8*)(&KV[j][h * 64]);
        }
        float s = 0.f;
#pragma unroll
        for (int e = 0; e < 8; ++e) {
            const bf16x8 qv = q8[e];
            const bf16x8 kv = k8[e];
#pragma unroll
            for (int x2 = 0; x2 < 8; ++x2)
                s += (float)qv[x2] * (float)kv[x2];
        }
        P[self ? h : 8 + h][i][j] = __float2bfloat16(s * 0.125f);
    }
    __syncthreads();

    // ---- softmax over j (96 self rows + 96 cross rows)
    if (tid < 192) {
        const int half = tid / 96, h = (tid % 96) / 12, i = tid % 12;
        const int tk = half ? tkc : 12;
        __hip_bfloat16* p = &P[half * 8 + h][i][0];
        float v[12];
        float mx = -1e30f;
        for (int j = 0; j < tk; ++j) { v[j] = __bfloat162float(p[j]); mx = fmaxf(mx, v[j]); }
        float sum = 0.f;
        for (int j = 0; j < tk; ++j) { v[j] = __expf(v[j] - mx); sum += v[j]; }
        const float inv = 1.f / sum;
        for (int j = 0; j < tk; ++j) p[j] = __float2bfloat16(v[j] * inv);
    }
    __syncthreads();

    // ---- AV: tasks = (i, g8) with g8 in [0,128): 0-63 self, 64-127 cross.
    // Each task: 8 output cols via bf16x8 V reads; one uint4 store.
    for (int idx = tid; idx < 12 * 128; idx += 512) {
        const int i = idx >> 7, g8 = idx & 127;
        float acc8[8] = {};
        int colbase;
        if (g8 < 64) {                 // self: V = R[:,1024:1536]
            const int h = g8 >> 3;
            colbase = g8 * 8;
#pragma unroll
            for (int j = 0; j < 12; ++j) {
                const float p = __bfloat162float(P[h][i][j]);
                const bf16x8 v = *(const bf16x8*)(&R[j][1024 + g8 * 8]);
#pragma unroll
                for (int e = 0; e < 8; ++e) acc8[e] += p * (float)v[e];
            }
        } else {                       // cross: V = KV[:,512:1024]
            const int cc = g8 - 64;
            const int h = cc >> 3;
            colbase = 512 + cc * 8;
            for (int j = 0; j < tkc; ++j) {
                const float p = __bfloat162float(P[8 + h][i][j]);
                const bf16x8 v = *(const bf16x8*)(&KV[j][512 + cc * 8]);
#pragma unroll
                for (int e = 0; e < 8; ++e) acc8[e] += p * (float)v[e];
            }
        }
        __hip_bfloat16 o[8];
#pragma unroll
        for (int e = 0; e < 8; ++e) o[e] = __float2bfloat16(acc8[e]);
        *(uint4*)(out + (size_t)(g * 12 + i) * 1024 + colbase) = *(const uint4*)o;
    }
}

// ---------------------------------------------------------------------------
extern "C" void kernel_launch(void* const* d_in, const int* in_sizes, int n_in,
                              void* d_out, int out_size, void* d_ws, size_t ws_size,
                              hipStream_t stream)
{
    (void)in_sizes; (void)n_in; (void)out_size; (void)ws_size;
    const float* x0        = (const float*)d_in[0];
    const float* x1        = (const float*)d_in[1];
    const float* wq_self   = (const float*)d_in[2];
    const float* wkv_self  = (const float*)d_in[3];
    const float* wq_cross  = (const float*)d_in[4];
    const float* wkv_cross = (const float*)d_in[5];
    const float* w_out     = (const float*)d_in[6];
    const float* b_out     = (const float*)d_in[7];

    // d_out doubles as the qkv scratch: 55296*2048*2 B == out_size*4 B exactly
    __hip_bfloat16* qkv = (__hip_bfloat16*)d_out;

    char* ws = (char*)d_ws;
    size_t off = 0;
    auto alloc = [&](size_t bytes) {
        void* p = ws + off;
        off += (bytes + 255) & ~(size_t)255;
        return p;
    };
    __hip_bfloat16* f0   = (__hip_bfloat16*)alloc((size_t)N0 * 1024 * 2);
    __hip_bfloat16* f1   = (__hip_bfloat16*)alloc((size_t)N1 * 512 * 2);
    __hip_bfloat16* kvc3 = (__hip_bfloat16*)alloc((size_t)N1 * 3072 * 2);
    __hip_bfloat16* W1t  = (__hip_bfloat16*)alloc((size_t)3 * 2048 * 1024 * 2);
    __hip_bfloat16* W2t  = (__hip_bfloat16*)alloc((size_t)3 * 1024 * 512 * 2);
    __hip_bfloat16* W3t  = (__hip_bfloat16*)alloc((size_t)3 * 1024 * 1024 * 2);
    __hip_bfloat16* W3o  = (__hip_bfloat16*)alloc((size_t)2 * 1024 * 1024 * 2);
    __hip_bfloat16* Wf   = (__hip_bfloat16*)alloc((size_t)2 * 2048 * 1024 * 2);
    float*          bfo  = (float*)alloc((size_t)2 * 2048 * 4);

    // ---- setup
    ln_all<<<N0 + N1, 256, 0, stream>>>(x0, x1, f0, f1);
    transpose_all<<<10752, 256, 0, stream>>>(wq_self, wkv_self, wq_cross,
                                             wkv_cross, w_out, W1t, W2t, W3t, W3o);
    bfold_kernel<<<16, 256, 0, stream>>>(b_out, W1t, bfo);
    // both weight folds in one z-batched launch:
    // Wf[j] = W1t[j+1] (A, [2048,1024]) x W3o[j] (Bt, [1024,1024])
    gemm8p<0, 0><<<dim3(4, 8, 2), 512, 0, stream>>>(
        W1t + (size_t)2048 * 1024, W3o, Wf, nullptr, nullptr,
        2048, 1024, 1024, 1024,
        (size_t)2048 * 1024, (size_t)1024 * 1024, (size_t)2048 * 1024);
    // all 3 cross-kv projections in one GEMM: [N1,512] @ [512,3072] -> kvc3
    gemm8p<0, 0><<<dim3(12, 54), 512, 0, stream>>>(
        f1, W2t, kvc3, nullptr, nullptr, N1, 3072, 512, 512, 0, 0, 0);

    // ---- 3 axial layers; qkv GEMM gathers A and writes layer layout L(ip)
    gemm8p<0, 1><<<dim3(8, 216), 512, 0, stream>>>(
        f0, W1t, qkv, nullptr, nullptr, N0, 2048, 1024, 1024, 0, 0, 0);
    attn_fused<<<4608, 512, 0, stream>>>(qkv, kvc3, f0, 0);

    gemm8p<1, 2><<<dim3(8, 216), 512, 0, stream>>>(
        f0, Wf, qkv, bfo, nullptr, N0, 2048, 1024, 1024, 0, 0, 0);
    attn_fused<<<4608, 512, 0, stream>>>(qkv, kvc3 + 1024, f0, 1);

    gemm8p<1, 3><<<dim3(8, 216), 512, 0, stream>>>(
        f0, Wf + (size_t)2048 * 1024, qkv, bfo + 2048, nullptr, N0, 2048, 1024, 1024, 0, 0, 0);
    attn_fused<<<4608, 512, 0, stream>>>(qkv, kvc3 + 2048, f0, 2);

    // ---- final out-proj: f0 (natural) @ W3t[2] + b[2] + x0 -> d_out (fp32)
    gemm8p<2, 0><<<dim3(4, 216), 512, 0, stream>>>(
        f0, W3t + (size_t)2 * 1024 * 1024, d_out, b_out + 2 * 1024, x0,
        N0, 1024, 1024, 1024, 0, 0, 0);
}

// Round 14
// 1451.164 us; speedup vs baseline: 1.3024x; 1.3024x over previous
//
#include <hip/hip_runtime.h>
#include <hip/hip_bf16.h>

// ---------------------------------------------------------------------------
// MultiFieldAxialAttention on MI355X (gfx950)
// B=32, T=12, LA=12, LO=12, D0=1024, D1=512, H=8+8, E=64
//
// Folds: qkv_{ip+1} = concat_ip @ (W3[ip]@W1[ip+1]) + b@W1[ip+1]; all 3
// cross-KV projections in one N=3072 GEMM; both weight-fold GEMMs z-batched.
// Layout pipeline: layer-ip qkv GEMM gathers A rows via digit permutation
// (per-lane global_load_lds source) and writes qkv with the attention axis
// innermost; attention reads/writes fully contiguous fibers.
// GEMM: round-9 schedule (best measured): 256x256x64, 4 phases/K-tile,
// one counted vmcnt(4)+barrier per phase, 16x16x32 MFMA, 0 bank conflicts.
// Attention: bf16x8-vectorized LDS reads (dots + AV), uint4 stores.
// (Round 14 = exact revert to the round-12 best-measured configuration.)
// ---------------------------------------------------------------------------

typedef __bf16 bf16x8 __attribute__((ext_vector_type(8)));
typedef float floatx4 __attribute__((ext_vector_type(4)));

#define N0 55296   // 32*12*12*12 tokens of field0
#define N1 13824   // 32*12*6*6 tokens of field1

#define RAW_BARRIER() asm volatile("s_barrier" ::: "memory")
#define VMCNT(n) asm volatile("s_waitcnt vmcnt(" #n ")" ::: "memory")
#define SCHED_FENCE() __builtin_amdgcn_sched_barrier(0)

__device__ __forceinline__ void gload16(const void* g, void* l) {
    __builtin_amdgcn_global_load_lds(
        (const __attribute__((address_space(1))) unsigned int*)g,
        (__attribute__((address_space(3))) unsigned int*)l, 16, 0, 0);
}

// Row map: C physical row i -> A physical row.  Digits of i in its layout:
// SIG 1: C=L0 (la,lo,t)   -> A natural (t,la,lo)
// SIG 2: C=L1 (t,lo,la)   -> A L0 (la,lo,t)
// SIG 3: C=natural(t,la,lo)-> A L1 (t,lo,la)
template <int SIG>
__device__ __forceinline__ int mapRow(int i) {
    if (SIG == 0) return i;
    const int b = i / 1728, r = i % 1728;
    const int d1 = r / 144, r2 = r % 144, d2 = r2 / 12, d3 = r2 % 12;
    if (SIG == 1) return b * 1728 + d3 * 144 + d1 * 12 + d2;
    if (SIG == 2) return b * 1728 + d3 * 144 + d2 * 12 + d1;
    return b * 1728 + d1 * 144 + d3 * 12 + d2;
}

// ---------------------------------------------------------------------------
// LayerNorm: fp32 in -> bf16 out, 1 block per row; vectorized loads/stores
// ---------------------------------------------------------------------------
template <int D>
__device__ __forceinline__ void ln_body(const float* __restrict__ xr,
                                        __hip_bfloat16* __restrict__ yr)
{
    constexpr int V = D / 256;          // 4 (D=1024) or 2 (D=512)
    const int tid = threadIdx.x;
    float vals[V];
    if constexpr (V == 4) {
        const float4 t4 = *(const float4*)(xr + tid * 4);
        vals[0] = t4.x; vals[1] = t4.y; vals[2] = t4.z; vals[3] = t4.w;
    } else {
        const float2 t2 = *(const float2*)(xr + tid * 2);
        vals[0] = t2.x; vals[1] = t2.y;
    }
    float s = 0.f, q = 0.f;
#pragma unroll
    for (int k = 0; k < V; ++k) { s += vals[k]; q += vals[k] * vals[k]; }
#pragma unroll
    for (int off = 32; off > 0; off >>= 1) {
        s += __shfl_xor(s, off);
        q += __shfl_xor(q, off);
    }
    __shared__ float rs[4], rq[4];
    const int w = tid >> 6;
    if ((tid & 63) == 0) { rs[w] = s; rq[w] = q; }
    __syncthreads();
    s = rs[0] + rs[1] + rs[2] + rs[3];
    q = rq[0] + rq[1] + rq[2] + rq[3];
    const float mean = s * (1.f / D);
    const float var  = q * (1.f / D) - mean * mean;
    const float rstd = rsqrtf(var + 1e-5f);
    __hip_bfloat16 o[V];
#pragma unroll
    for (int k = 0; k < V; ++k) o[k] = __float2bfloat16((vals[k] - mean) * rstd);
    if constexpr (V == 4) *(uint2*)(yr + tid * 4) = *(const uint2*)o;
    else                  *(uint*)(yr + tid * 2)  = *(const uint*)o;
}

__global__ __launch_bounds__(256)
void ln_all(const float* __restrict__ x0, const float* __restrict__ x1,
            __hip_bfloat16* __restrict__ f0, __hip_bfloat16* __restrict__ f1)
{
    const int row = blockIdx.x;
    if (row < N0) {
        ln_body<1024>(x0 + (size_t)row * 1024, f0 + (size_t)row * 1024);
    } else {
        const int r = row - N0;
        ln_body<512>(x1 + (size_t)r * 512, f1 + (size_t)r * 512);
    }
}

// ---------------------------------------------------------------------------
// Weight transposes (W3t only for ip=2 -- ip 0,1 are folded away) + w_out
// bf16 cast, in ONE launch. transpose: [K][N] fp32 -> [N][K] bf16.
// Segments: [0,1536) wq_self, [1536,4608) wkv_self, [4608,6144) wq_cross,
// [6144,7680) wkv_cross, [7680,8704) w_out ip2 -> W3t[2],
// [8704,10752) flat cast w_out[0..1] -> W3o.
// ---------------------------------------------------------------------------
__global__ __launch_bounds__(256)
void transpose_all(const float* __restrict__ wqs, const float* __restrict__ wkvs,
                   const float* __restrict__ wqc, const float* __restrict__ wkvc,
                   const float* __restrict__ wo,
                   __hip_bfloat16* __restrict__ W1t,
                   __hip_bfloat16* __restrict__ W2t,
                   __hip_bfloat16* __restrict__ W3t,
                   __hip_bfloat16* __restrict__ W3o)
{
    int idx = blockIdx.x;
    if (idx >= 8704) {   // flat cast segment: w_out[0..1] -> W3o
        const size_t i = ((size_t)(idx - 8704) * 256 + threadIdx.x) * 4;
        const float4 v = *(const float4*)(wo + i);
        __hip_bfloat16 o[4] = { __float2bfloat16(v.x), __float2bfloat16(v.y),
                                __float2bfloat16(v.z), __float2bfloat16(v.w) };
        *(uint2*)(W3o + i) = *(const uint2*)o;
        return;
    }
    const float* src;
    __hip_bfloat16* dst;
    int K, N;
    if (idx < 1536) {
        const int ip = idx / 512; idx %= 512; K = 1024; N = 512;
        src = wqs + (size_t)ip * 524288;  dst = W1t + (size_t)ip * 2097152;
    } else if (idx < 4608) {
        idx -= 1536;
        const int ip = idx / 1024; idx %= 1024; K = 1024; N = 1024;
        src = wkvs + (size_t)ip * 1048576; dst = W1t + (size_t)ip * 2097152 + 524288;
    } else if (idx < 6144) {
        idx -= 4608;
        const int ip = idx / 512; idx %= 512; K = 1024; N = 512;
        src = wqc + (size_t)ip * 524288;  dst = W1t + (size_t)ip * 2097152 + 1572864;
    } else if (idx < 7680) {
        idx -= 6144;
        const int ip = idx / 512; idx %= 512; K = 512; N = 1024;
        src = wkvc + (size_t)ip * 524288; dst = W2t + (size_t)ip * 524288;
    } else {
        idx -= 7680;   // [0,1024): w_out ip=2 only
        K = 1024; N = 1024;
        src = wo + (size_t)2 * 1048576;  dst = W3t + (size_t)2 * 1048576;
    }
    const int tiles_x = N >> 5;
    const int n0 = (idx % tiles_x) * 32, k0 = (idx / tiles_x) * 32;

    __shared__ float tile[32][33];
    const int tx = threadIdx.x & 31, ty = threadIdx.x >> 5; // 32 x 8
#pragma unroll
    for (int d = 0; d < 4; ++d)
        tile[ty + d * 8][tx] = src[(size_t)(k0 + ty + d * 8) * N + n0 + tx];
    __syncthreads();
#pragma unroll
    for (int d = 0; d < 4; ++d)
        dst[(size_t)(n0 + ty + d * 8) * K + k0 + tx] = __float2bfloat16(tile[tx][ty + d * 8]);
}

// ---------------------------------------------------------------------------
// Folded bias: bf[j][n] = sum_d b_out[j][d] * W1[j+1][d][n]  (j = 0,1)
// ---------------------------------------------------------------------------
__global__ __launch_bounds__(256)
void bfold_kernel(const float* __restrict__ b_out,
                  const __hip_bfloat16* __restrict__ W1t,
                  float* __restrict__ bf)
{
    const int idx = blockIdx.x * 256 + threadIdx.x;   // [0, 4096)
    const int j = idx >> 11, n = idx & 2047;
    const float* b = b_out + j * 1024;
    const __hip_bfloat16* w = W1t + ((size_t)(j + 1) * 2048 + n) * 1024;
    float s = 0.f;
#pragma unroll 4
    for (int d = 0; d < 1024; ++d) s += b[d] * __bfloat162float(w[d]);
    bf[idx] = s;
}

// ---------------------------------------------------------------------------
// 256x256 bf16 MFMA GEMM: C[M,N] = A[sigma(M),K] @ Bt[N,K]^T   (round-9)
// 512 thr = 8 waves (2Mx4N), per-wave 128x64 out, 16x16x32 MFMA, BK=64,
// dbuf LDS 128 KiB. 4 phases/K-tile, one counted vmcnt(4)+barrier per phase;
// P3 reads next tile's A-h0 from the landed prefetch. XOR swizzle on 16B
// col-groups (pre-swizzled global src, rule 21) = 0 bank conflicts.
// zsA/zsB/zsC: blockIdx.z batch strides in elements (z>1 only with EPI=0).
// EPI: 0 = bf16 ; 1 = bf16+bias ; 2 = fp32+bias+resid
// ---------------------------------------------------------------------------
template <int EPI, int SIG>
__global__ __launch_bounds__(512)
void gemm8p(const __hip_bfloat16* __restrict__ A,
            const __hip_bfloat16* __restrict__ Bt,
            void* __restrict__ Cv,
            const float* __restrict__ bias,
            const float* __restrict__ resid,
            int M, int N, int K, int lda,
            size_t zsA, size_t zsB, size_t zsC)
{
    __shared__ __align__(16) char lds[131072];

    A  += (size_t)blockIdx.z * zsA;
    Bt += (size_t)blockIdx.z * zsB;
    Cv = (void*)((__hip_bfloat16*)Cv + (size_t)blockIdx.z * zsC);

    // bijective XCD swizzle (all grids are multiples of 8 workgroups per z)
    const int gx  = gridDim.x;
    const int nwg = gx * gridDim.y;
    const int bid = blockIdx.y * gx + blockIdx.x;
    const int swz = (bid & 7) * (nwg >> 3) + (bid >> 3);
    const int m0 = (swz / gx) * 256;
    const int n0 = (swz % gx) * 256;

    const int t    = threadIdx.x;
    const int w    = t >> 6;
    const int lane = t & 63;
    const int wr   = w >> 2;     // 0..1  (M half)
    const int wc   = w & 3;      // 0..3  (N quarter)
    const int fr   = lane & 15;
    const int ksl  = lane >> 4;

    floatx4 acc[8][4] = {};

    // ---- staging source bases (pre-swizzled col: key = local row & 7)
    const int tr   = t >> 3;                      // 0..63
    const int scol = ((t & 7) ^ (tr & 7)) << 3;
    const __hip_bfloat16* aP[4];
#pragma unroll
    for (int r = 0; r < 4; ++r)
        aP[r] = A + (size_t)mapRow<SIG>(m0 + tr + r * 64) * lda + scol;
    const __hip_bfloat16* bG = Bt + (size_t)(n0 + ((tr >> 5) * 64) + (tr & 31)) * K + scol;
    const int ldst = t * 16;                      // linear LDS dest

    // ---- ds_read per-thread base offsets (kk=1 via ^64)
    const int cg0 = ksl ^ (fr & 7);
    const int aO0 = (wr * 64 + fr) * 128 + cg0 * 16;
    const int bO0 = (wc * 32 + fr) * 128 + cg0 * 16;

    // LDS map per buffer (64 KiB): A-h0 @0, A-h1 @16384, B-h0 @32768, B-h1 @49152
    auto stageA = [&](char* buf, int h, int ka) {
        gload16(aP[h]     + ka, buf + h * 16384 + ldst);
        gload16(aP[h + 2] + ka, buf + h * 16384 + 8192 + ldst);
    };
    auto stageB = [&](char* buf, int h, int kb) {
        gload16(bG + kb + (size_t)(h * 32)       * K, buf + 32768 + h * 16384 + ldst);
        gload16(bG + kb + (size_t)(h * 32 + 128) * K, buf + 32768 + h * 16384 + 8192 + ldst);
    };

    const char* bufC = lds;
    auto ldA = [&](int h, bf16x8 (&a)[2][4]) {
#pragma unroll
        for (int mm = 0; mm < 4; ++mm) {
            a[0][mm] = *(const bf16x8*)(bufC + h * 16384 + mm * 2048 + aO0);
            a[1][mm] = *(const bf16x8*)(bufC + h * 16384 + mm * 2048 + (aO0 ^ 64));
        }
    };
    auto ldB = [&](int h, bf16x8 (&b)[2][2]) {
#pragma unroll
        for (int nn = 0; nn < 2; ++nn) {
            b[0][nn] = *(const bf16x8*)(bufC + 32768 + h * 16384 + nn * 2048 + bO0);
            b[1][nn] = *(const bf16x8*)(bufC + 32768 + h * 16384 + nn * 2048 + (bO0 ^ 64));
        }
    };
    auto quad = [&](bf16x8 (&a)[2][4], bf16x8 (&b)[2][2], int mlo, int nlo) {
        __builtin_amdgcn_s_setprio(1);
#pragma unroll
        for (int kk = 0; kk < 2; ++kk)
#pragma unroll
            for (int mm = 0; mm < 4; ++mm)
#pragma unroll
                for (int nn = 0; nn < 2; ++nn)
                    acc[mlo + mm][nlo + nn] = __builtin_amdgcn_mfma_f32_16x16x32_bf16(
                        a[kk][mm], b[kk][nn], acc[mlo + mm][nlo + nn], 0, 0, 0);
        __builtin_amdgcn_s_setprio(0);
    };

    const int NT = K >> 6;

    // prologue: stage tile 0 (FIFO A0,B0,A1,B1); A0,B0 landed; read a0(t0)
    stageA(lds, 0, 0);
    stageB(lds, 0, 0);
    stageA(lds, 1, 0);
    stageB(lds, 1, 0);
    VMCNT(4);
    RAW_BARRIER();

    bf16x8 a0[2][4], a1[2][4], b0[2][2], b1[2][2];
    ldA(0, a0);

    for (int tt = 0; tt < NT - 1; ++tt) {
        bufC = lds + ((tt & 1) << 16);
        char* bufN = lds + (((tt + 1) & 1) << 16);
        const int kc = (tt + 1) << 6;
        // P0: read b0(t); stage A0(t+1); MFMA (m0-3, n0-1)
        ldB(0, b0);
        stageA(bufN, 0, kc);
        SCHED_FENCE();
        quad(a0, b0, 0, 0);
        VMCNT(4); RAW_BARRIER();
        // P1: read a1(t); stage B0(t+1); MFMA (m4-7, n0-1)
        ldA(1, a1);
        stageB(bufN, 0, kc);
        SCHED_FENCE();
        quad(a1, b0, 4, 0);
        VMCNT(4); RAW_BARRIER();
        // P2: read b1(t); stage A1(t+1); MFMA (m0-3, n2-3)
        ldB(1, b1);
        stageA(bufN, 1, kc);
        SCHED_FENCE();
        quad(a0, b1, 0, 2);
        VMCNT(4); RAW_BARRIER();
        // P3: read a0(t+1) from next buffer (A0(t+1) landed: end-P2 wait);
        //     stage B1(t+1); MFMA (m4-7, n2-3)
        bufC = bufN;
        ldA(0, a0);
        stageB(bufN, 1, kc);
        SCHED_FENCE();
        quad(a1, b1, 4, 2);
        VMCNT(4); RAW_BARRIER();
    }

    // tail tile NT-1 (a0 already in regs; no prefetch): waits 2 -> 0
    bufC = lds + (((NT - 1) & 1) << 16);
    ldB(0, b0);
    SCHED_FENCE();
    quad(a0, b0, 0, 0);
    VMCNT(2); RAW_BARRIER();
    ldA(1, a1);
    SCHED_FENCE();
    quad(a1, b0, 4, 0);
    VMCNT(0); RAW_BARRIER();
    ldB(1, b1);
    SCHED_FENCE();
    quad(a0, b1, 0, 2);
    quad(a1, b1, 4, 2);

    // ---- epilogue (C rows are physically linear)
#pragma unroll
    for (int m = 0; m < 8; ++m) {
#pragma unroll
        for (int n = 0; n < 4; ++n) {
            const int col = n0 + wc * 64 + n * 16 + fr;
#pragma unroll
            for (int r = 0; r < 4; ++r) {
                const int row = m0 + wr * 128 + m * 16 + ksl * 4 + r;
                const size_t idx = (size_t)row * N + col;
                const float v = acc[m][n][r];
                if (EPI == 0) {
                    ((__hip_bfloat16*)Cv)[idx] = __float2bfloat16(v);
                } else if (EPI == 1) {
                    ((__hip_bfloat16*)Cv)[idx] = __float2bfloat16(v + bias[col]);
                } else {
                    ((float*)Cv)[idx] = resid[idx] + v + bias[col];
                }
            }
        }
    }
}

// ---------------------------------------------------------------------------
// Fused axial attention (self + cross in one block), layout-contiguous,
// bf16x8-vectorized LDS reads.
// qkv rows [g*12, g*12+12) in layer layout L(ip): [q_self|k_self|v_self|q_cross]
// kvc: layer slice of kvc3 (row stride 3072): [k_cross(512) | v_cross(512)]
// out: concat [o_self|o_cross] rows [g*12, g*12+12), ld 1024 (layout L(ip))
// ---------------------------------------------------------------------------
__global__ __launch_bounds__(512)
void attn_fused(const __hip_bfloat16* __restrict__ qkv,
                const __hip_bfloat16* __restrict__ kvc,
                __hip_bfloat16* __restrict__ out, int ip)
{
    __shared__ __align__(16) __hip_bfloat16 R[12][2056];   // rows 4112B = 16B-aligned
    __shared__ __align__(16) __hip_bfloat16 KV[12][1032];  // rows 2064B = 16B-aligned
    __shared__ __hip_bfloat16 P[16][12][12];               // 8 self + 8 cross

    const int g   = blockIdx.x;           // 4608 fibers
    const int tid = threadIdx.x;

    // decode fiber -> cross-kv base (g digits are in layout L(ip) order)
    const int b  = g / 144;
    const int u1 = (g / 12) % 12;
    const int u2 = g % 12;
    int kvb, kvstride, tkc;
    if (ip == 0) {        // L0 fiber coords (la, lo); kv along t
        kvb = b * 432 + (u1 >> 1) * 6 + (u2 >> 1); kvstride = 36; tkc = 12;
    } else if (ip == 1) { // L1 fiber coords (t, lo); kv along la'
        kvb = b * 432 + u1 * 36 + (u2 >> 1); kvstride = 6; tkc = 6;
    } else {              // natural fiber coords (t, la); kv along lo'
        kvb = b * 432 + u1 * 36 + (u2 >> 1) * 6; kvstride = 1; tkc = 6;
    }

    // ---- stage 12 full rows (48KB contiguous)
    const uint4* src = (const uint4*)(qkv + (size_t)g * 12 * 2048);
    for (int idx = tid; idx < 12 * 256; idx += 512) {
        const int row = idx >> 8, cg = idx & 255;
        *(uint4*)(&R[row][cg * 8]) = src[row * 256 + cg];
    }
    // ---- stage cross K/V (2KB per kv row)
    for (int idx = tid; idx < tkc * 128; idx += 512) {
        const int row = idx >> 7, cg = idx & 127;
        const uint4* kvr = (const uint4*)(kvc + (size_t)(kvb + row * kvstride) * 3072);
        *(uint4*)(&KV[row][cg * 8]) = kvr[cg];
    }
    __syncthreads();

    // ---- dots (self: 1152, cross: 8*12*tkc), bf16x8 reads
    const int nd_self = 8 * 12 * 12;
    const int nd = nd_self + 8 * 12 * tkc;
    for (int idx = tid; idx < nd; idx += 512) {
        int h, i, j;
        const bf16x8 *q8, *k8;
        const bool self = idx < nd_self;
        if (self) {
            h = idx / 144; const int rem = idx % 144; i = rem / 12; j = rem % 12;
            q8 = (const bf16x8*)(&R[i][h * 64]);
            k8 = (const bf16x8*)(&R[j][512 + h * 64]);
        } else {
            const int x = idx - nd_self;
            h = x / (12 * tkc); const int rem = x % (12 * tkc); i = rem / tkc; j = rem % tkc;
            q8 = (const bf16x8*)(&R[i][1536 + h * 64]);
            k8 = (const bf16x8*)(&KV[j][h * 64]);
        }
        float s = 0.f;
#pragma unroll
        for (int e = 0; e < 8; ++e) {
            const bf16x8 qv = q8[e];
            const bf16x8 kv = k8[e];
#pragma unroll
            for (int x2 = 0; x2 < 8; ++x2)
                s += (float)qv[x2] * (float)kv[x2];
        }
        P[self ? h : 8 + h][i][j] = __float2bfloat16(s * 0.125f);
    }
    __syncthreads();

    // ---- softmax over j (96 self rows + 96 cross rows)
    if (tid < 192) {
        const int half = tid / 96, h = (tid % 96) / 12, i = tid % 12;
        const int tk = half ? tkc : 12;
        __hip_bfloat16* p = &P[half * 8 + h][i][0];
        float v[12];
        float mx = -1e30f;
        for (int j = 0; j < tk; ++j) { v[j] = __bfloat162float(p[j]); mx = fmaxf(mx, v[j]); }
        float sum = 0.f;
        for (int j = 0; j < tk; ++j) { v[j] = __expf(v[j] - mx); sum += v[j]; }
        const float inv = 1.f / sum;
        for (int j = 0; j < tk; ++j) p[j] = __float2bfloat16(v[j] * inv);
    }
    __syncthreads();

    // ---- AV: tasks = (i, g8) with g8 in [0,128): 0-63 self, 64-127 cross.
    // Each task: 8 output cols via bf16x8 V reads; one uint4 store.
    for (int idx = tid; idx < 12 * 128; idx += 512) {
        const int i = idx >> 7, g8 = idx & 127;
        float acc8[8] = {};
        int colbase;
        if (g8 < 64) {                 // self: V = R[:,1024:1536]
            const int h = g8 >> 3;
            colbase = g8 * 8;
#pragma unroll
            for (int j = 0; j < 12; ++j) {
                const float p = __bfloat162float(P[h][i][j]);
                const bf16x8 v = *(const bf16x8*)(&R[j][1024 + g8 * 8]);
#pragma unroll
                for (int e = 0; e < 8; ++e) acc8[e] += p * (float)v[e];
            }
        } else {                       // cross: V = KV[:,512:1024]
            const int cc = g8 - 64;
            const int h = cc >> 3;
            colbase = 512 + cc * 8;
            for (int j = 0; j < tkc; ++j) {
                const float p = __bfloat162float(P[8 + h][i][j]);
                const bf16x8 v = *(const bf16x8*)(&KV[j][512 + cc * 8]);
#pragma unroll
                for (int e = 0; e < 8; ++e) acc8[e] += p * (float)v[e];
            }
        }
        __hip_bfloat16 o[8];
#pragma unroll
        for (int e = 0; e < 8; ++e) o[e] = __float2bfloat16(acc8[e]);
        *(uint4*)(out + (size_t)(g * 12 + i) * 1024 + colbase) = *(const uint4*)o;
    }
}

// ---------------------------------------------------------------------------
extern "C" void kernel_launch(void* const* d_in, const int* in_sizes, int n_in,
                              void* d_out, int out_size, void* d_ws, size_t ws_size,
                              hipStream_t stream)
{
    (void)in_sizes; (void)n_in; (void)out_size; (void)ws_size;
    const float* x0        = (const float*)d_in[0];
    const float* x1        = (const float*)d_in[1];
    const float* wq_self   = (const float*)d_in[2];
    const float* wkv_self  = (const float*)d_in[3];
    const float* wq_cross  = (const float*)d_in[4];
    const float* wkv_cross = (const float*)d_in[5];
    const float* w_out     = (const float*)d_in[6];
    const float* b_out     = (const float*)d_in[7];

    // d_out doubles as the qkv scratch: 55296*2048*2 B == out_size*4 B exactly
    __hip_bfloat16* qkv = (__hip_bfloat16*)d_out;

    char* ws = (char*)d_ws;
    size_t off = 0;
    auto alloc = [&](size_t bytes) {
        void* p = ws + off;
        off += (bytes + 255) & ~(size_t)255;
        return p;
    };
    __hip_bfloat16* f0   = (__hip_bfloat16*)alloc((size_t)N0 * 1024 * 2);
    __hip_bfloat16* f1   = (__hip_bfloat16*)alloc((size_t)N1 * 512 * 2);
    __hip_bfloat16* kvc3 = (__hip_bfloat16*)alloc((size_t)N1 * 3072 * 2);
    __hip_bfloat16* W1t  = (__hip_bfloat16*)alloc((size_t)3 * 2048 * 1024 * 2);
    __hip_bfloat16* W2t  = (__hip_bfloat16*)alloc((size_t)3 * 1024 * 512 * 2);
    __hip_bfloat16* W3t  = (__hip_bfloat16*)alloc((size_t)3 * 1024 * 1024 * 2);
    __hip_bfloat16* W3o  = (__hip_bfloat16*)alloc((size_t)2 * 1024 * 1024 * 2);
    __hip_bfloat16* Wf   = (__hip_bfloat16*)alloc((size_t)2 * 2048 * 1024 * 2);
    float*          bfo  = (float*)alloc((size_t)2 * 2048 * 4);

    // ---- setup
    ln_all<<<N0 + N1, 256, 0, stream>>>(x0, x1, f0, f1);
    transpose_all<<<10752, 256, 0, stream>>>(wq_self, wkv_self, wq_cross,
                                             wkv_cross, w_out, W1t, W2t, W3t, W3o);
    bfold_kernel<<<16, 256, 0, stream>>>(b_out, W1t, bfo);
    // both weight folds in one z-batched launch:
    // Wf[j] = W1t[j+1] (A, [2048,1024]) x W3o[j] (Bt, [1024,1024])
    gemm8p<0, 0><<<dim3(4, 8, 2), 512, 0, stream>>>(
        W1t + (size_t)2048 * 1024, W3o, Wf, nullptr, nullptr,
        2048, 1024, 1024, 1024,
        (size_t)2048 * 1024, (size_t)1024 * 1024, (size_t)2048 * 1024);
    // all 3 cross-kv projections in one GEMM: [N1,512] @ [512,3072] -> kvc3
    gemm8p<0, 0><<<dim3(12, 54), 512, 0, stream>>>(
        f1, W2t, kvc3, nullptr, nullptr, N1, 3072, 512, 512, 0, 0, 0);

    // ---- 3 axial layers; qkv GEMM gathers A and writes layer layout L(ip)
    gemm8p<0, 1><<<dim3(8, 216), 512, 0, stream>>>(
        f0, W1t, qkv, nullptr, nullptr, N0, 2048, 1024, 1024, 0, 0, 0);
    attn_fused<<<4608, 512, 0, stream>>>(qkv, kvc3, f0, 0);

    gemm8p<1, 2><<<dim3(8, 216), 512, 0, stream>>>(
        f0, Wf, qkv, bfo, nullptr, N0, 2048, 1024, 1024, 0, 0, 0);
    attn_fused<<<4608, 512, 0, stream>>>(qkv, kvc3 + 1024, f0, 1);

    gemm8p<1, 3><<<dim3(8, 216), 512, 0, stream>>>(
        f0, Wf + (size_t)2048 * 1024, qkv, bfo + 2048, nullptr, N0, 2048, 1024, 1024, 0, 0, 0);
    attn_fused<<<4608, 512, 0, stream>>>(qkv, kvc3 + 2048, f0, 2);

    // ---- final out-proj: f0 (natural) @ W3t[2] + b[2] + x0 -> d_out (fp32)
    gemm8p<2, 0><<<dim3(4, 216), 512, 0, stream>>>(
        f0, W3t + (size_t)2 * 1024 * 1024, d_out, b_out + 2 * 1024, x0,
        N0, 1024, 1024, 1024, 0, 0, 0);
}